// Round 7
// baseline (455.868 us; speedup 1.0000x reference)
//
#include <hip/hip_runtime.h>
#include <hip/hip_bf16.h>

// EdgeDetourHead: B=2, N=512, E=128, H=256
// h1 = relu( [ |h_i-h_j| | h_j | e_ij ] @ [W1c; W1b; w1d] + PA[i] )  (PA = h_i@W1a + b1, fp32)
// h2 = relu( h1@W2 + b2 ) ;  p = h2@W3 + b3 ;  out = 0.5*(p+p^T), zero diag
//
// R7: persistent pipelined WGs on the R6 transposed dataflow.
// 256 WGs x 512 thr (8 waves), 1 WG/CU (141 KB LDS). WG owns (b, jt, 16 i's):
// hj + node j-rows are tile-invariant (built once); D double-buffered.
// Per tile: spanA = [store p(t-1) | K1(t) MFMA/LDSr/VMEM interleaved with
// buildD(t+1) global/VALU/LDSw] ; epi1 ; spanB = [K2 + L3-in-regs + pp].
// Wave (ntg, mt2): 2 m-tiles x 2 n-tiles = 4 acc (64 VGPR) - no R4 spill.

#define BN 512
#define EE 128
#define HH 256

typedef __attribute__((ext_vector_type(8)))  short short8;
typedef __attribute__((ext_vector_type(4)))  short short4v;
typedef __attribute__((ext_vector_type(16))) float f32x16;
typedef __attribute__((ext_vector_type(4)))  float f32x4;

static __device__ __forceinline__ unsigned short f2bf(float f) {
    __bf16 h = (__bf16)f;
    return __builtin_bit_cast(unsigned short, h);
}
static __device__ __forceinline__ f32x16 zero16() {
    f32x16 v;
    #pragma unroll
    for (int i = 0; i < 16; ++i) v[i] = 0.f;
    return v;
}
#define MFMA(a, b, c) __builtin_amdgcn_mfma_f32_32x32x16_bf16((a), (b), (c), 0, 0, 0)

// ---------------- kernel 0: prep = weight pack (blocks 0..255) + PA (blocks 256..1279) ----
// Packed frag idx = ((kb*8 + mtile)*64 + l)*8 + t ; value W[kb*16+(l>>5)*8+t][mtile*32+(l&31)]
// == A-frag of W^T for the transposed kernel.
__global__ void prep(const float* __restrict__ node, const float* __restrict__ W1,
                     const float* __restrict__ W2, const float* __restrict__ b1,
                     float* __restrict__ PA,
                     unsigned short* __restrict__ w1c_p, unsigned short* __restrict__ w1b_p,
                     unsigned short* __restrict__ w2_p,  unsigned short* __restrict__ w1d_f) {
    int blk = blockIdx.x;
    if (blk < 256) {
        int idx = blk * 256 + threadIdx.x;             // 0..65535
        {                                              // W2^T A-frags: kb 0..15
            int t = idx & 7, l = (idx >> 3) & 63, mt = (idx >> 9) & 7, kb = idx >> 12;
            int k = kb * 16 + (l >> 5) * 8 + t, m = mt * 32 + (l & 31);
            w2_p[idx] = f2bf(W2[k * HH + m]);
            if (idx < 32768) {                         // W1c^T, W1b^T: kb 0..7
                w1c_p[idx] = f2bf(W1[(2 * EE + k) * HH + m]);
                w1b_p[idx] = f2bf(W1[(EE + k) * HH + m]);
            }
        }
        if (idx < 4096) {                              // w1d^T rank-1 A-frags (k=0 col)
            int t = idx & 7, l = (idx >> 3) & 63, mt = idx >> 9;
            int m = mt * 32 + (l & 31);
            bool nz = (t == 0 && l < 32);
            w1d_f[idx] = nz ? f2bf(W1[(3 * EE) * HH + m]) : (unsigned short)0;
        }
    } else {
        int bi = blk - 256;                            // 0..1023
        int h = threadIdx.x;
        const float* nd = node + (size_t)bi * EE;
        float sa = b1[h];
        #pragma unroll 8
        for (int e = 0; e < EE; ++e) sa += nd[e] * W1[e * HH + h];
        PA[bi * HH + h] = sa;
    }
}

// ---------------- kernel 1: persistent pipelined main ----------------
__global__ __launch_bounds__(512, 2) void edge_main(
    const float* __restrict__ node, const float* __restrict__ euclid,
    const float* __restrict__ W3, const float* __restrict__ b3,
    const float* __restrict__ b2v, const float* __restrict__ PA,
    const unsigned short* __restrict__ w1c_p, const unsigned short* __restrict__ w1b_p,
    const unsigned short* __restrict__ w2_p,  const unsigned short* __restrict__ w1d_f,
    float* __restrict__ out)
{
    // 4 regions of 128x136 shorts (34816 B) + pp: 141312 B total (1 WG/CU).
    __shared__ __align__(16) unsigned short Rd[2][128 * 136];  // D dbuf / h1-low overlay
    __shared__ __align__(16) unsigned short Rh[128 * 136];     // h1-high (feats 128..255)
    __shared__ __align__(16) unsigned short Rhj[128 * 136];    // hj (persistent)
    __shared__ float pp[512];

    const int wg = blockIdx.x;
    const int b = wg >> 7, jt = (wg >> 5) & 3, ig = wg & 31;
    const int jbase = jt * 128, i0 = ig * 16;
    const int tid = threadIdx.x, wave = tid >> 6, lane = tid & 63;
    const int m0 = lane & 31, q = lane >> 5;
    const int mt2 = wave & 3, ntg = wave >> 2;         // wave owns m-tiles {2mt2,2mt2+1} x n-tiles {2ntg,2ntg+1}
    const int nt0 = 2 * ntg, nt1 = 2 * ntg + 1;

    // build-phase mapping: 4 threads/row, 32 cols each
    const int brow = tid >> 2, bq4 = tid & 3;
    const f32x4* njp = (const f32x4*)(node + ((size_t)b * BN + jbase + brow) * EE);  // WG-invariant rows

    const float b3v = b3[0];
    const short8 aw0 = ((const short8*)w1d_f)[(2 * mt2 + 0) * 64 + lane];
    const short8 aw1 = ((const short8*)w1d_f)[(2 * mt2 + 1) * 64 + lane];
    const short8* wc  = (const short8*)w1c_p;
    const short8* wb  = (const short8*)w1b_p;
    const short8* w2f = (const short8*)w2_p;

    // ---- prologue: build HJ (persistent) + D(0) ----
    {
        const f32x4* hv = (const f32x4*)(node + ((size_t)b * BN + i0) * EE);
        #pragma unroll
        for (int k = 0; k < 4; ++k) {
            int c0 = bq4 * 8 + k * 2;
            f32x4 a0 = njp[c0], a1 = njp[c0 + 1];
            f32x4 h0 = hv[c0],  h1v = hv[c0 + 1];
            short8 pd, ph;
            #pragma unroll
            for (int u = 0; u < 4; ++u) {
                pd[u]     = (short)f2bf(fabsf(a0[u] - h0[u]));
                pd[4 + u] = (short)f2bf(fabsf(a1[u] - h1v[u]));
                ph[u]     = (short)f2bf(a0[u]);
                ph[4 + u] = (short)f2bf(a1[u]);
            }
            int off = brow * 136 + bq4 * 32 + k * 8;
            *(short8*)&Rd[0][off]  = pd;
            *(short8*)&Rhj[off]    = ph;
        }
    }
    __syncthreads();

    #pragma unroll 1
    for (int tt = 0; tt < 16; ++tt) {
        const int i = i0 + tt;
        unsigned short* Dcur = Rd[tt & 1];
        unsigned short* Dnxt = Rd[(tt + 1) & 1];

        // -------- span A: store p(t-1) + K1(t) interleaved with buildD(t+1) --------
        if (tt > 0 && tid < 128) {
            float v = pp[tid * 4] + pp[tid * 4 + 1] + pp[tid * 4 + 2] + pp[tid * 4 + 3] + b3v;
            out[((size_t)b * BN + (i - 1)) * BN + jbase + tid] = v;
        }

        f32x16 acc[2][2];
        acc[0][0] = zero16(); acc[0][1] = zero16();
        acc[1][0] = zero16(); acc[1][1] = zero16();
        {
            const f32x4* hvn = (const f32x4*)(node + ((size_t)b * BN + i + 1) * EE);
            #pragma unroll
            for (int kb = 0; kb < 8; ++kb) {
                // buildD(t+1) chunk (heterogeneous work inside the MFMA loop)
                if (kb < 4 && tt < 15) {
                    int c0 = bq4 * 8 + kb * 2;
                    f32x4 a0 = njp[c0], a1 = njp[c0 + 1];
                    f32x4 h0 = hvn[c0], h1v = hvn[c0 + 1];
                    short8 pd;
                    #pragma unroll
                    for (int u = 0; u < 4; ++u) {
                        pd[u]     = (short)f2bf(fabsf(a0[u] - h0[u]));
                        pd[4 + u] = (short)f2bf(fabsf(a1[u] - h1v[u]));
                    }
                    *(short8*)&Dnxt[brow * 136 + bq4 * 32 + kb * 8] = pd;
                }
                // K1 step
                short8 ac0 = wc[(kb * 8 + 2 * mt2 + 0) * 64 + lane];
                short8 ac1 = wc[(kb * 8 + 2 * mt2 + 1) * 64 + lane];
                short8 ab0 = wb[(kb * 8 + 2 * mt2 + 0) * 64 + lane];
                short8 ab1 = wb[(kb * 8 + 2 * mt2 + 1) * 64 + lane];
                int o0 = (nt0 * 32 + m0) * 136 + kb * 16 + q * 8;
                int o1 = (nt1 * 32 + m0) * 136 + kb * 16 + q * 8;
                short8 bD0 = *(const short8*)&Dcur[o0];
                short8 bD1 = *(const short8*)&Dcur[o1];
                short8 bH0 = *(const short8*)&Rhj[o0];
                short8 bH1 = *(const short8*)&Rhj[o1];
                acc[0][0] = MFMA(ac0, bD0, acc[0][0]);
                acc[1][0] = MFMA(ac1, bD0, acc[1][0]);
                acc[0][1] = MFMA(ac0, bD1, acc[0][1]);
                acc[1][1] = MFMA(ac1, bD1, acc[1][1]);
                acc[0][0] = MFMA(ab0, bH0, acc[0][0]);
                acc[1][0] = MFMA(ab1, bH0, acc[1][0]);
                acc[0][1] = MFMA(ab0, bH1, acc[0][1]);
                acc[1][1] = MFMA(ab1, bH1, acc[1][1]);
            }
            // rank-1 e*w1d
            const float* erow = euclid + ((size_t)b * BN + i) * BN + jbase;
            #pragma unroll
            for (int nt2 = 0; nt2 < 2; ++nt2) {
                short8 be;
                #pragma unroll
                for (int u = 0; u < 8; ++u) be[u] = 0;
                if (lane < 32) be[0] = (short)f2bf(erow[(nt0 + nt2) * 32 + m0]);
                acc[0][nt2] = MFMA(aw0, be, acc[0][nt2]);
                acc[1][nt2] = MFMA(aw1, be, acc[1][nt2]);
            }
        }
        __syncthreads();   // A: K1 done reading Dcur; buildD(t+1) committed

        // -------- epi1: h1 = relu(acc + PA) -> [Dcur (feats 0..127) | Rh (128..255)] --------
        {
            const float* paB = PA + ((size_t)b * BN + i) * HH;
            unsigned short* base = (mt2 < 2) ? Dcur : Rh;
            #pragma unroll
            for (int mtl = 0; mtl < 2; ++mtl) {
                int mt = 2 * mt2 + mtl;
                #pragma unroll
                for (int rg = 0; rg < 4; ++rg) {
                    int f0 = mt * 32 + rg * 8 + 4 * q;
                    f32x4 pav = *(const f32x4*)&paB[f0];
                    int lc = f0 & 127;
                    #pragma unroll
                    for (int nt2 = 0; nt2 < 2; ++nt2) {
                        short4v w;
                        #pragma unroll
                        for (int u = 0; u < 4; ++u) {
                            float v = acc[mtl][nt2][rg * 4 + u] + pav[u];
                            v = v > 0.f ? v : 0.f;
                            w[u] = (short)f2bf(v);
                        }
                        *(short4v*)&base[((nt0 + nt2) * 32 + m0) * 136 + lc] = w;
                    }
                }
            }
        }
        __syncthreads();   // B

        // -------- span B: K2 + L3 in registers + pp --------
        f32x16 c2[2][2];
        c2[0][0] = zero16(); c2[0][1] = zero16();
        c2[1][0] = zero16(); c2[1][1] = zero16();
        {
            #pragma unroll
            for (int kb = 0; kb < 16; ++kb) {
                const unsigned short* src = (kb < 8) ? Dcur : Rh;
                short8 a0 = w2f[(kb * 8 + 2 * mt2 + 0) * 64 + lane];
                short8 a1 = w2f[(kb * 8 + 2 * mt2 + 1) * 64 + lane];
                int o0 = (nt0 * 32 + m0) * 136 + (kb & 7) * 16 + q * 8;
                int o1 = (nt1 * 32 + m0) * 136 + (kb & 7) * 16 + q * 8;
                short8 bh0 = *(const short8*)&src[o0];
                short8 bh1 = *(const short8*)&src[o1];
                c2[0][0] = MFMA(a0, bh0, c2[0][0]);
                c2[1][0] = MFMA(a1, bh0, c2[1][0]);
                c2[0][1] = MFMA(a0, bh1, c2[0][1]);
                c2[1][1] = MFMA(a1, bh1, c2[1][1]);
            }
        }
        {
            float s0 = 0.f, s1 = 0.f;
            #pragma unroll
            for (int mtl = 0; mtl < 2; ++mtl) {
                #pragma unroll
                for (int rg = 0; rg < 4; ++rg) {
                    int f0 = (2 * mt2 + mtl) * 32 + rg * 8 + 4 * q;
                    f32x4 bb = *(const f32x4*)&b2v[f0];
                    f32x4 ww = *(const f32x4*)&W3[f0];
                    #pragma unroll
                    for (int u = 0; u < 4; ++u) {
                        float h2a = c2[mtl][0][rg * 4 + u] + bb[u];
                        h2a = h2a > 0.f ? h2a : 0.f;
                        s0 += h2a * ww[u];
                        float h2b = c2[mtl][1][rg * 4 + u] + bb[u];
                        h2b = h2b > 0.f ? h2b : 0.f;
                        s1 += h2b * ww[u];
                    }
                }
            }
            s0 += __shfl_xor(s0, 32, 64);
            s1 += __shfl_xor(s1, 32, 64);
            if (lane < 32) {
                pp[(nt0 * 32 + lane) * 4 + mt2] = s0;
                pp[(nt1 * 32 + lane) * 4 + mt2] = s1;
            }
        }
        __syncthreads();   // C
    }

    // final store p(15)
    if (tid < 128) {
        float v = pp[tid * 4] + pp[tid * 4 + 1] + pp[tid * 4 + 2] + pp[tid * 4 + 3] + b3v;
        out[((size_t)b * BN + (i0 + 15)) * BN + jbase + tid] = v;
    }
}

// ---------------- kernel 2: in-place symmetrize + zero diagonal ----------------
__global__ void symmetrize(float* __restrict__ out) {
    int b = blockIdx.z, ti = blockIdx.y, tj = blockIdx.x;
    if (tj < ti) return;
    int i = ti * 32 + threadIdx.y, j = tj * 32 + threadIdx.x;
    float* p = out + (size_t)b * BN * BN;
    if (i == j) { p[(size_t)i * BN + j] = 0.f; return; }
    if (j < i) return;
    float a = p[(size_t)i * BN + j];
    float c = p[(size_t)j * BN + i];
    float v = 0.5f * (a + c);
    p[(size_t)i * BN + j] = v;
    p[(size_t)j * BN + i] = v;
}

extern "C" void kernel_launch(void* const* d_in, const int* in_sizes, int n_in,
                              void* d_out, int out_size, void* d_ws, size_t ws_size,
                              hipStream_t stream) {
    const float* node   = (const float*)d_in[0];
    const float* euclid = (const float*)d_in[2];
    const float* W1     = (const float*)d_in[3];
    const float* b1     = (const float*)d_in[4];
    const float* W2     = (const float*)d_in[5];
    const float* b2     = (const float*)d_in[6];
    const float* W3     = (const float*)d_in[7];
    const float* b3     = (const float*)d_in[8];
    float* out = (float*)d_out;

    char* ws = (char*)d_ws;
    float*          PA    = (float*)ws;                                   // 1 MB
    unsigned short* w1c_p = (unsigned short*)(ws + (1u << 20));           // 64 KB
    unsigned short* w1b_p = (unsigned short*)(ws + (1u << 20) + 65536);   // 64 KB
    unsigned short* w2_p  = (unsigned short*)(ws + (1u << 20) + 131072);  // 128 KB
    unsigned short* w1d_f = (unsigned short*)(ws + (1u << 20) + 262144);  // 8 KB

    prep<<<1280, 256, 0, stream>>>(node, W1, W2, b1, PA, w1c_p, w1b_p, w2_p, w1d_f);
    edge_main<<<256, 512, 0, stream>>>(
        node, euclid, W3, b3, b2, PA, w1c_p, w1b_p, w2_p, w1d_f, out);
    symmetrize<<<dim3(BN / 32, BN / 32, 2), dim3(32, 32), 0, stream>>>(out);
}

// Round 8
// 270.745 us; speedup vs baseline: 1.6838x; 1.6838x over previous
//
#include <hip/hip_runtime.h>
#include <hip/hip_bf16.h>

// EdgeDetourHead: B=2, N=512, E=128, H=256
// h1 = relu( PA[i] + PB[j] + |h_i-h_j|@W1c + e_ij*w1d )   PA = h_i@W1a + b1 (fp32)
//                                                          PB = h_j@W1b      (fp32)
// h2 = relu( h1@W2 + b2 ) ;  p = h2@W3 + b3 ;  out = 0.5*(p+p^T), zero diag
//
// R8: R6's transposed phase-separated structure (proven best) + algebraic cut:
//  - PB precomputed exactly in prep; K1 accumulators INITIALIZED from a PB
//    gather (replaces the hj@W1b MFMA block: -64 MFMA, -hj build, -hj LDS)
//  - persistent WG over 8 i's at fixed (b,jt); id&7=(b,jt) -> XCD-local stripes
//  - opaque asm offset per tile defeats LICM of tile-invariant streams
//    (the R4/R7 spill mode). NO cross-phase interleaving - that always spilled.

#define BN 512
#define EE 128
#define HH 256

typedef __attribute__((ext_vector_type(8)))  short short8;
typedef __attribute__((ext_vector_type(4)))  short short4v;
typedef __attribute__((ext_vector_type(16))) float f32x16;
typedef __attribute__((ext_vector_type(4)))  float f32x4;

static __device__ __forceinline__ unsigned short f2bf(float f) {
    __bf16 h = (__bf16)f;
    return __builtin_bit_cast(unsigned short, h);
}
static __device__ __forceinline__ f32x16 zero16() {
    f32x16 v;
    #pragma unroll
    for (int i = 0; i < 16; ++i) v[i] = 0.f;
    return v;
}
#define MFMA(a, b, c) __builtin_amdgcn_mfma_f32_32x32x16_bf16((a), (b), (c), 0, 0, 0)

// ---------------- kernel 0: prep = weight pack (blocks 0..255) + PA/PB (256..1279) ----
// Packed frag idx = ((kb*8 + mtile)*64 + l)*8 + t ; value W[kb*16+(l>>5)*8+t][mtile*32+(l&31)]
// == A-frag of W^T for the transposed kernel.
__global__ void prep(const float* __restrict__ node, const float* __restrict__ W1,
                     const float* __restrict__ W2, const float* __restrict__ b1,
                     float* __restrict__ PA, float* __restrict__ PB,
                     unsigned short* __restrict__ w1c_p, unsigned short* __restrict__ w2_p,
                     unsigned short* __restrict__ w1d_f) {
    int blk = blockIdx.x;
    if (blk < 256) {
        int idx = blk * 256 + threadIdx.x;             // 0..65535
        {                                              // W2^T A-frags: kb 0..15
            int t = idx & 7, l = (idx >> 3) & 63, mt = (idx >> 9) & 7, kb = idx >> 12;
            int k = kb * 16 + (l >> 5) * 8 + t, m = mt * 32 + (l & 31);
            w2_p[idx] = f2bf(W2[k * HH + m]);
            if (idx < 32768)                           // W1c^T: rows 256..383
                w1c_p[idx] = f2bf(W1[(2 * EE + k) * HH + m]);
        }
        if (idx < 4096) {                              // w1d^T rank-1 A-frags (k=0 col)
            int t = idx & 7, l = (idx >> 3) & 63, mt = idx >> 9;
            int m = mt * 32 + (l & 31);
            bool nz = (t == 0 && l < 32);
            w1d_f[idx] = nz ? f2bf(W1[(3 * EE) * HH + m]) : (unsigned short)0;
        }
    } else {
        int bi = blk - 256;                            // 0..1023
        int h = threadIdx.x;
        const float* nd = node + (size_t)bi * EE;
        float sa = b1[h], sb = 0.f;
        #pragma unroll 4
        for (int e = 0; e < EE; ++e) {
            float x = nd[e];
            sa += x * W1[e * HH + h];
            sb += x * W1[(EE + e) * HH + h];
        }
        PA[bi * HH + h] = sa;
        PB[bi * HH + h] = sb;
    }
}

// ---------------- kernel 1: fused main, persistent over 8 i's at fixed (b,jt) ----------
// Wave w owns feature m-tiles {2w,2w+1} (64 feats) x all 4 pair n-tiles -> 8 acc tiles.
__global__ __launch_bounds__(256, 2) void edge_main(
    const float* __restrict__ node, const float* __restrict__ euclid,
    const float* __restrict__ W3, const float* __restrict__ b3,
    const float* __restrict__ b2v, const float* __restrict__ PA,
    const float* __restrict__ PB,
    const unsigned short* __restrict__ w1c_p, const unsigned short* __restrict__ w2_p,
    const unsigned short* __restrict__ w1d_f,
    float* __restrict__ out)
{
    // D: front, stride 136 (17408 shorts). h1: whole buffer, stride 264 (33792 shorts).
    __shared__ __align__(16) unsigned short lds_buf[128 * 264];   // 67584 B -> 2 WG/CU
    __shared__ float pp[512];

    const int id = blockIdx.x;                 // id&7 = (b,jt) -> XCD-local stripes
    const int ig = id >> 3, b = (id >> 2) & 1, jt = id & 3;
    const int jbase = jt * 128, i0 = ig * 8;
    const int tid = threadIdx.x, wave = tid >> 6, lane = tid & 63;
    const int m0 = lane & 31, q = lane >> 5;
    const int brow = tid >> 1, bhalf = tid & 1;

    const float b3v = b3[0];
    const short8 aw0 = ((const short8*)w1d_f)[(wave * 2 + 0) * 64 + lane];
    const short8 aw1 = ((const short8*)w1d_f)[(wave * 2 + 1) * 64 + lane];
    const float* pbBase = PB + ((size_t)b * BN + jbase) * HH;
    int prow[4];
    #pragma unroll
    for (int nt = 0; nt < 4; ++nt) prow[nt] = (nt * 32 + m0) * HH;

    #pragma unroll 1
    for (int tt = 0; tt < 8; ++tt) {
        const int i = i0 + tt;
        // Opaque zero offset: compiler cannot prove tile-invariance of these
        // streams -> no cross-tile LICM -> no R4/R7-style register spill.
        size_t z = 0;
        asm volatile("" : "+s"(z));
        const short8* wcT = (const short8*)w1c_p + z;
        const short8* w2T = (const short8*)w2_p + z;
        const float*  pbT = pbBase + z;
        const f32x4*  njT = (const f32x4*)(node + ((size_t)b * BN + jbase + brow) * EE) + z;
        const float*  b2T = b2v + z;
        const float*  w3T = W3 + z;

        // ---- phase 0: acc := PB gather (fp32, replaces hj@W1b MFMA); e preload ----
        f32x16 acc[2][4];
        #pragma unroll
        for (int mtl = 0; mtl < 2; ++mtl) {
            #pragma unroll
            for (int rg = 0; rg < 4; ++rg) {
                int f0 = wave * 64 + mtl * 32 + rg * 8 + 4 * q;
                #pragma unroll
                for (int nt = 0; nt < 4; ++nt) {
                    f32x4 v = *(const f32x4*)&pbT[prow[nt] + f0];
                    #pragma unroll
                    for (int u = 0; u < 4; ++u) acc[mtl][nt][rg * 4 + u] = v[u];
                }
            }
        }
        const float* erow = euclid + ((size_t)b * BN + i) * BN + jbase;
        float ev[4];
        #pragma unroll
        for (int nt = 0; nt < 4; ++nt) ev[nt] = erow[nt * 32 + m0];

        // ---- phase 1: build D = |h_i-h_j| bf16 row-major [pair][e], stride 136 ----
        {
            const f32x4* hv = (const f32x4*)(node + ((size_t)b * BN + i) * EE);
            #pragma unroll
            for (int g = 0; g < 8; ++g) {
                int c0 = bhalf * 16 + g * 2;
                f32x4 a0 = njT[c0], a1 = njT[c0 + 1];
                f32x4 h0 = hv[c0],  h1v = hv[c0 + 1];
                short8 pd;
                #pragma unroll
                for (int u = 0; u < 4; ++u) {
                    pd[u]     = (short)f2bf(fabsf(a0[u] - h0[u]));
                    pd[4 + u] = (short)f2bf(fabsf(a1[u] - h1v[u]));
                }
                *(short8*)&lds_buf[brow * 136 + bhalf * 64 + g * 8] = pd;
            }
        }
        __syncthreads();

        // ---- phase 2: K1 = W1c^T @ D^T + rank-1 e*w1d ----
        {
            #pragma unroll
            for (int kb = 0; kb < 8; ++kb) {
                short8 ac0 = wcT[(kb * 8 + wave * 2 + 0) * 64 + lane];
                short8 ac1 = wcT[(kb * 8 + wave * 2 + 1) * 64 + lane];
                #pragma unroll
                for (int nt = 0; nt < 4; ++nt) {
                    short8 bD = *(const short8*)&lds_buf[(nt * 32 + m0) * 136 + kb * 16 + q * 8];
                    acc[0][nt] = MFMA(ac0, bD, acc[0][nt]);
                    acc[1][nt] = MFMA(ac1, bD, acc[1][nt]);
                }
            }
            #pragma unroll
            for (int nt = 0; nt < 4; ++nt) {
                short8 be;
                #pragma unroll
                for (int u = 0; u < 8; ++u) be[u] = 0;
                if (lane < 32) be[0] = (short)f2bf(ev[nt]);
                acc[0][nt] = MFMA(aw0, be, acc[0][nt]);
                acc[1][nt] = MFMA(aw1, be, acc[1][nt]);
            }
        }
        __syncthreads();   // D dead; h1 overwrites

        // ---- phase 3: epi1: h1 = relu(acc + PA) -> stride 264, b64 writes ----
        {
            const float* paB = PA + ((size_t)b * BN + i) * HH;
            #pragma unroll
            for (int mtl = 0; mtl < 2; ++mtl) {
                #pragma unroll
                for (int rg = 0; rg < 4; ++rg) {
                    int f0 = wave * 64 + mtl * 32 + rg * 8 + 4 * q;
                    f32x4 pav = *(const f32x4*)&paB[f0];
                    #pragma unroll
                    for (int nt = 0; nt < 4; ++nt) {
                        short4v w;
                        #pragma unroll
                        for (int u = 0; u < 4; ++u) {
                            float v = acc[mtl][nt][rg * 4 + u] + pav[u];
                            v = v > 0.f ? v : 0.f;
                            w[u] = (short)f2bf(v);
                        }
                        *(short4v*)&lds_buf[(nt * 32 + m0) * 264 + f0] = w;
                    }
                }
            }
        }
        __syncthreads();

        // ---- phase 4: K2 = W2^T @ h1^T ----
        f32x16 c2[2][4];
        #pragma unroll
        for (int mtl = 0; mtl < 2; ++mtl)
            #pragma unroll
            for (int nt = 0; nt < 4; ++nt) c2[mtl][nt] = zero16();
        {
            #pragma unroll
            for (int kb = 0; kb < 16; ++kb) {
                short8 a0 = w2T[(kb * 8 + wave * 2 + 0) * 64 + lane];
                short8 a1 = w2T[(kb * 8 + wave * 2 + 1) * 64 + lane];
                #pragma unroll
                for (int nt = 0; nt < 4; ++nt) {
                    short8 bh = *(const short8*)&lds_buf[(nt * 32 + m0) * 264 + kb * 16 + q * 8];
                    c2[0][nt] = MFMA(a0, bh, c2[0][nt]);
                    c2[1][nt] = MFMA(a1, bh, c2[1][nt]);
                }
            }
        }

        // ---- phase 5: L3 in registers: s[nt] = sum_f relu(c2 + b2[f]) * W3[f] ----
        {
            float s[4] = {0.f, 0.f, 0.f, 0.f};
            #pragma unroll
            for (int mtl = 0; mtl < 2; ++mtl) {
                #pragma unroll
                for (int rg = 0; rg < 4; ++rg) {
                    int f0 = wave * 64 + mtl * 32 + rg * 8 + 4 * q;
                    f32x4 bb = *(const f32x4*)&b2T[f0];
                    f32x4 ww = *(const f32x4*)&w3T[f0];
                    #pragma unroll
                    for (int u = 0; u < 4; ++u) {
                        #pragma unroll
                        for (int nt = 0; nt < 4; ++nt) {
                            float h2 = c2[mtl][nt][rg * 4 + u] + bb[u];
                            h2 = h2 > 0.f ? h2 : 0.f;
                            s[nt] += h2 * ww[u];
                        }
                    }
                }
            }
            #pragma unroll
            for (int nt = 0; nt < 4; ++nt)
                s[nt] += __shfl_xor(s[nt], 32, 64);    // fold q-halves (same pair)
            if (lane < 32) {
                #pragma unroll
                for (int nt = 0; nt < 4; ++nt)
                    pp[wave * 128 + nt * 32 + lane] = s[nt];
            }
        }
        __syncthreads();
        if (tid < 128) {
            float v = pp[tid] + pp[128 + tid] + pp[256 + tid] + pp[384 + tid] + b3v;
            out[((size_t)b * BN + i) * BN + jbase + tid] = v;
        }
        // next tile's phase-1 writes lds_buf: all K2 reads completed before the
        // sync above; pp is untouched until 3 syncs later -> safe.
    }
}

// ---------------- kernel 2: in-place symmetrize + zero diagonal ----------------
__global__ void symmetrize(float* __restrict__ out) {
    int b = blockIdx.z, ti = blockIdx.y, tj = blockIdx.x;
    if (tj < ti) return;
    int i = ti * 32 + threadIdx.y, j = tj * 32 + threadIdx.x;
    float* p = out + (size_t)b * BN * BN;
    if (i == j) { p[(size_t)i * BN + j] = 0.f; return; }
    if (j < i) return;
    float a = p[(size_t)i * BN + j];
    float c = p[(size_t)j * BN + i];
    float v = 0.5f * (a + c);
    p[(size_t)i * BN + j] = v;
    p[(size_t)j * BN + i] = v;
}

extern "C" void kernel_launch(void* const* d_in, const int* in_sizes, int n_in,
                              void* d_out, int out_size, void* d_ws, size_t ws_size,
                              hipStream_t stream) {
    const float* node   = (const float*)d_in[0];
    const float* euclid = (const float*)d_in[2];
    const float* W1     = (const float*)d_in[3];
    const float* b1     = (const float*)d_in[4];
    const float* W2     = (const float*)d_in[5];
    const float* b2     = (const float*)d_in[6];
    const float* W3     = (const float*)d_in[7];
    const float* b3     = (const float*)d_in[8];
    float* out = (float*)d_out;

    char* ws = (char*)d_ws;
    float*          PA    = (float*)ws;                                   // 1 MB
    float*          PB    = (float*)(ws + (1u << 20));                    // 1 MB
    unsigned short* w1c_p = (unsigned short*)(ws + (2u << 20));           // 64 KB
    unsigned short* w2_p  = (unsigned short*)(ws + (2u << 20) + 65536);   // 128 KB
    unsigned short* w1d_f = (unsigned short*)(ws + (2u << 20) + 196608);  // 8 KB

    prep<<<1280, 256, 0, stream>>>(node, W1, W2, b1, PA, PB, w1c_p, w2_p, w1d_f);
    edge_main<<<512, 256, 0, stream>>>(
        node, euclid, W3, b3, b2, PA, PB, w1c_p, w2_p, w1d_f, out);
    symmetrize<<<dim3(BN / 32, BN / 32, 2), dim3(32, 32), 0, stream>>>(out);
}

// Round 9
// 251.452 us; speedup vs baseline: 1.8129x; 1.0767x over previous
//
#include <hip/hip_runtime.h>
#include <hip/hip_bf16.h>

// EdgeDetourHead: B=2, N=512, E=128, H=256
// h1 = relu( [ |h_i-h_j| | h_j | e_ij ] @ [W1c; W1b; w1d] + PA[i] )  (PA = h_i@W1a + b1, fp32)
// h2 = relu( h1@W2 + b2 ) ;  p = h2@W3 + b3 ;  out = 0.5*(p+p^T), zero diag
//
// R9 = R6 (best, 184us) phases UNCHANGED + two additions:
//  1. persistent WGs: 512 WGs x 8 i-tiles at fixed (b,jt); id&7 -> XCD-local.
//     Tile-invariant streams behind an opaque asm offset (R8-proven: no spill).
//  2. anti-lockstep stagger: waves in odd HW wave-slots sleep ~24K cycles once
//     at start, displacing the two co-resident WGs by ~half a tile period so
//     one WG's MFMA phases overlap the other's VALU/LDS phases (sum->max).

#define BN 512
#define EE 128
#define HH 256

typedef __attribute__((ext_vector_type(8)))  short short8;
typedef __attribute__((ext_vector_type(4)))  short short4v;
typedef __attribute__((ext_vector_type(16))) float f32x16;
typedef __attribute__((ext_vector_type(4)))  float f32x4;

static __device__ __forceinline__ unsigned short f2bf(float f) {
    __bf16 h = (__bf16)f;
    return __builtin_bit_cast(unsigned short, h);
}
static __device__ __forceinline__ f32x16 zero16() {
    f32x16 v;
    #pragma unroll
    for (int i = 0; i < 16; ++i) v[i] = 0.f;
    return v;
}
#define MFMA(a, b, c) __builtin_amdgcn_mfma_f32_32x32x16_bf16((a), (b), (c), 0, 0, 0)

// ---------------- kernel 0: prep = weight pack (blocks 0..255) + PA (256..1279) ----
// Packed frag idx = ((kb*8 + mtile)*64 + l)*8 + t ; value W[kb*16+(l>>5)*8+t][mtile*32+(l&31)]
// == A-frag of W^T for the transposed kernel.
__global__ void prep(const float* __restrict__ node, const float* __restrict__ W1,
                     const float* __restrict__ W2, const float* __restrict__ b1,
                     float* __restrict__ PA,
                     unsigned short* __restrict__ w1c_p, unsigned short* __restrict__ w1b_p,
                     unsigned short* __restrict__ w2_p,  unsigned short* __restrict__ w1d_f) {
    int blk = blockIdx.x;
    if (blk < 256) {
        int idx = blk * 256 + threadIdx.x;             // 0..65535
        {                                              // W2^T A-frags: kb 0..15
            int t = idx & 7, l = (idx >> 3) & 63, mt = (idx >> 9) & 7, kb = idx >> 12;
            int k = kb * 16 + (l >> 5) * 8 + t, m = mt * 32 + (l & 31);
            w2_p[idx] = f2bf(W2[k * HH + m]);
            if (idx < 32768) {                         // W1c^T, W1b^T: kb 0..7
                w1c_p[idx] = f2bf(W1[(2 * EE + k) * HH + m]);
                w1b_p[idx] = f2bf(W1[(EE + k) * HH + m]);
            }
        }
        if (idx < 4096) {                              // w1d^T rank-1 A-frags (k=0 col)
            int t = idx & 7, l = (idx >> 3) & 63, mt = idx >> 9;
            int m = mt * 32 + (l & 31);
            bool nz = (t == 0 && l < 32);
            w1d_f[idx] = nz ? f2bf(W1[(3 * EE) * HH + m]) : (unsigned short)0;
        }
    } else {
        int bi = blk - 256;                            // 0..1023
        int h = threadIdx.x;
        const float* nd = node + (size_t)bi * EE;
        float sa = b1[h];
        #pragma unroll 8
        for (int e = 0; e < EE; ++e) sa += nd[e] * W1[e * HH + h];
        PA[bi * HH + h] = sa;
    }
}

// ---------------- kernel 1: persistent fused main (8 tiles per WG) ----------------
// Wave w owns feature m-tiles {2w,2w+1} x all 4 pair n-tiles -> 8 acc tiles.
__global__ __launch_bounds__(256, 2) void edge_main(
    const float* __restrict__ node, const float* __restrict__ euclid,
    const float* __restrict__ W3, const float* __restrict__ b3,
    const float* __restrict__ b2v, const float* __restrict__ PA,
    const unsigned short* __restrict__ w1c_p, const unsigned short* __restrict__ w1b_p,
    const unsigned short* __restrict__ w2_p,  const unsigned short* __restrict__ w1d_f,
    float* __restrict__ out)
{
    // Phase 1/K1: D [128][136] + hj [128][136] (69632 B). epi1 on: h1 [128][264].
    __shared__ __align__(16) unsigned short lds_buf[2 * 128 * 136];
    __shared__ float pp[512];

    // ---- anti-lockstep stagger: odd wave-slot => sleep ~24K cycles once ----
    {
        int hwid = 0;
        asm volatile("s_getreg_b32 %0, hwreg(HW_REG_HW_ID, 0, 4)" : "=s"(hwid));
        if (hwid & 1) {
            __builtin_amdgcn_s_sleep(127);             // ~8128 clk each
            __builtin_amdgcn_s_sleep(127);
            __builtin_amdgcn_s_sleep(127);
        }
    }

    const int id = blockIdx.x;                 // id&7 = (jt,b) -> XCD-local stripes
    const int jt = id & 3, b = (id >> 2) & 1, ig = id >> 3;
    const int jbase = jt * 128, i0 = ig * 8;
    const int tid = threadIdx.x, wave = tid >> 6, lane = tid & 63;
    const int m0 = lane & 31, q = lane >> 5;
    const int brow = tid >> 1, bhalf = tid & 1;

    unsigned short* ldsD  = lds_buf;
    unsigned short* ldsHJ = lds_buf + 128 * 136;
    unsigned short* ldsH1 = lds_buf;                   // overwrites D+hj after K1

    const float b3v = b3[0];
    const short8 aw0 = ((const short8*)w1d_f)[(wave * 2 + 0) * 64 + lane];
    const short8 aw1 = ((const short8*)w1d_f)[(wave * 2 + 1) * 64 + lane];

    #pragma unroll 1
    for (int tt = 0; tt < 8; ++tt) {
        const int i = i0 + tt;
        // Opaque zero offset: blocks cross-tile LICM of invariant streams
        // (R4/R7 spill mode); SGPR-cheap reload per tile instead.
        size_t z = 0;
        asm volatile("" : "+s"(z));
        const short8* wcT = (const short8*)w1c_p + z;
        const short8* wbT = (const short8*)w1b_p + z;
        const short8* w2T = (const short8*)w2_p + z;
        const f32x4*  njT = (const f32x4*)(node + ((size_t)b * BN + jbase + brow) * EE) + z;
        const float*  b2T = b2v + z;
        const float*  w3T = W3 + z;

        // ---- phase 1: build D=|h_i-h_j| and hj (bf16) row-major, stride 136 ----
        {
            const f32x4* hv = (const f32x4*)(node + ((size_t)b * BN + i) * EE);
            #pragma unroll
            for (int g = 0; g < 8; ++g) {
                int c0 = bhalf * 16 + g * 2;           // f32x4 index
                f32x4 a0 = njT[c0], a1 = njT[c0 + 1];
                f32x4 h0 = hv[c0],  h1v = hv[c0 + 1];
                short8 pd, ph;
                #pragma unroll
                for (int u = 0; u < 4; ++u) {
                    pd[u]     = (short)f2bf(fabsf(a0[u] - h0[u]));
                    pd[4 + u] = (short)f2bf(fabsf(a1[u] - h1v[u]));
                    ph[u]     = (short)f2bf(a0[u]);
                    ph[4 + u] = (short)f2bf(a1[u]);
                }
                int off = brow * 136 + bhalf * 64 + g * 8;
                *(short8*)&ldsD[off]  = pd;
                *(short8*)&ldsHJ[off] = ph;
            }
        }
        __syncthreads();

        // ---- layer 1 (transposed): C1^T = W1c^T@D^T + W1b^T@hj^T + w1d^T@e^T ----
        f32x16 acc[2][4];
        #pragma unroll
        for (int mt = 0; mt < 2; ++mt)
            #pragma unroll
            for (int nt = 0; nt < 4; ++nt) acc[mt][nt] = zero16();
        {
            const int mtg = wave * 2;
            #pragma unroll
            for (int kb = 0; kb < 8; ++kb) {
                short8 ac0 = wcT[(kb * 8 + mtg + 0) * 64 + lane];
                short8 ac1 = wcT[(kb * 8 + mtg + 1) * 64 + lane];
                short8 ab0 = wbT[(kb * 8 + mtg + 0) * 64 + lane];
                short8 ab1 = wbT[(kb * 8 + mtg + 1) * 64 + lane];
                #pragma unroll
                for (int nt = 0; nt < 4; ++nt) {
                    int off = (nt * 32 + m0) * 136 + kb * 16 + q * 8;
                    short8 bD  = *(const short8*)&ldsD[off];
                    short8 bHJ = *(const short8*)&ldsHJ[off];
                    acc[0][nt] = MFMA(ac0, bD, acc[0][nt]);
                    acc[1][nt] = MFMA(ac1, bD, acc[1][nt]);
                    acc[0][nt] = MFMA(ab0, bHJ, acc[0][nt]);
                    acc[1][nt] = MFMA(ab1, bHJ, acc[1][nt]);
                }
            }
            // rank-1 e*w1d
            const float* erow = euclid + ((size_t)b * BN + i) * BN + jbase;
            #pragma unroll
            for (int nt = 0; nt < 4; ++nt) {
                short8 be;
                #pragma unroll
                for (int u = 0; u < 8; ++u) be[u] = 0;
                if (lane < 32) be[0] = (short)f2bf(erow[nt * 32 + m0]);
                acc[0][nt] = MFMA(aw0, be, acc[0][nt]);
                acc[1][nt] = MFMA(aw1, be, acc[1][nt]);
            }
        }
        __syncthreads();   // D + hj dead

        // ---- epi1: h1[pair][feat] = relu(C1^T + PA[feat]) -> stride 264, b64 ----
        {
            const float* paB = PA + ((size_t)b * BN + i) * HH;
            #pragma unroll
            for (int mt = 0; mt < 2; ++mt) {
                #pragma unroll
                for (int rg = 0; rg < 4; ++rg) {
                    int f0 = wave * 64 + mt * 32 + rg * 8 + 4 * q;
                    f32x4 pav = *(const f32x4*)&paB[f0];
                    #pragma unroll
                    for (int nt = 0; nt < 4; ++nt) {
                        short4v w;
                        #pragma unroll
                        for (int u = 0; u < 4; ++u) {
                            float v = acc[mt][nt][rg * 4 + u] + pav[u];
                            v = v > 0.f ? v : 0.f;
                            w[u] = (short)f2bf(v);
                        }
                        *(short4v*)&ldsH1[(nt * 32 + m0) * 264 + f0] = w;
                    }
                }
            }
        }
        __syncthreads();

        // ---- layer 2 (transposed): C2^T = W2^T @ h1^T ----
        f32x16 c2[2][4];
        #pragma unroll
        for (int mt = 0; mt < 2; ++mt)
            #pragma unroll
            for (int nt = 0; nt < 4; ++nt) c2[mt][nt] = zero16();
        {
            const int mtg = wave * 2;
            #pragma unroll
            for (int kb = 0; kb < 16; ++kb) {
                short8 a0 = w2T[(kb * 8 + mtg + 0) * 64 + lane];
                short8 a1 = w2T[(kb * 8 + mtg + 1) * 64 + lane];
                #pragma unroll
                for (int nt = 0; nt < 4; ++nt) {
                    short8 bh = *(const short8*)&ldsH1[(nt * 32 + m0) * 264 + kb * 16 + q * 8];
                    c2[0][nt] = MFMA(a0, bh, c2[0][nt]);
                    c2[1][nt] = MFMA(a1, bh, c2[1][nt]);
                }
            }
        }

        // ---- layer 3 in registers: s[nt] = sum_f relu(c2 + b2[f]) * W3[f] ----
        {
            float s[4] = {0.f, 0.f, 0.f, 0.f};
            #pragma unroll
            for (int mt = 0; mt < 2; ++mt) {
                #pragma unroll
                for (int rg = 0; rg < 4; ++rg) {
                    int f0 = wave * 64 + mt * 32 + rg * 8 + 4 * q;
                    f32x4 bb = *(const f32x4*)&b2T[f0];
                    f32x4 ww = *(const f32x4*)&w3T[f0];
                    #pragma unroll
                    for (int u = 0; u < 4; ++u) {
                        #pragma unroll
                        for (int nt = 0; nt < 4; ++nt) {
                            float h2 = c2[mt][nt][rg * 4 + u] + bb[u];
                            h2 = h2 > 0.f ? h2 : 0.f;
                            s[nt] += h2 * ww[u];
                        }
                    }
                }
            }
            #pragma unroll
            for (int nt = 0; nt < 4; ++nt)
                s[nt] += __shfl_xor(s[nt], 32, 64);    // fold q-halves (same pair)
            if (lane < 32) {
                #pragma unroll
                for (int nt = 0; nt < 4; ++nt)
                    pp[wave * 128 + nt * 32 + lane] = s[nt];
            }
        }
        __syncthreads();
        if (tid < 128) {
            float v = pp[tid] + pp[128 + tid] + pp[256 + tid] + pp[384 + tid] + b3v;
            out[((size_t)b * BN + i) * BN + jbase + tid] = v;
        }
        // next iteration's build writes lds_buf only after this sync; pp is
        // read here and rewritten 4 syncs later -> safe.
    }
}

// ---------------- kernel 2: in-place symmetrize + zero diagonal ----------------
__global__ void symmetrize(float* __restrict__ out) {
    int b = blockIdx.z, ti = blockIdx.y, tj = blockIdx.x;
    if (tj < ti) return;
    int i = ti * 32 + threadIdx.y, j = tj * 32 + threadIdx.x;
    float* p = out + (size_t)b * BN * BN;
    if (i == j) { p[(size_t)i * BN + j] = 0.f; return; }
    if (j < i) return;
    float a = p[(size_t)i * BN + j];
    float c = p[(size_t)j * BN + i];
    float v = 0.5f * (a + c);
    p[(size_t)i * BN + j] = v;
    p[(size_t)j * BN + i] = v;
}

extern "C" void kernel_launch(void* const* d_in, const int* in_sizes, int n_in,
                              void* d_out, int out_size, void* d_ws, size_t ws_size,
                              hipStream_t stream) {
    const float* node   = (const float*)d_in[0];
    const float* euclid = (const float*)d_in[2];
    const float* W1     = (const float*)d_in[3];
    const float* b1     = (const float*)d_in[4];
    const float* W2     = (const float*)d_in[5];
    const float* b2     = (const float*)d_in[6];
    const float* W3     = (const float*)d_in[7];
    const float* b3     = (const float*)d_in[8];
    float* out = (float*)d_out;

    char* ws = (char*)d_ws;
    float*          PA    = (float*)ws;                                   // 1 MB
    unsigned short* w1c_p = (unsigned short*)(ws + (1u << 20));           // 64 KB
    unsigned short* w1b_p = (unsigned short*)(ws + (1u << 20) + 65536);   // 64 KB
    unsigned short* w2_p  = (unsigned short*)(ws + (1u << 20) + 131072);  // 128 KB
    unsigned short* w1d_f = (unsigned short*)(ws + (1u << 20) + 262144);  // 8 KB

    prep<<<1280, 256, 0, stream>>>(node, W1, W2, b1, PA, w1c_p, w1b_p, w2_p, w1d_f);
    edge_main<<<512, 256, 0, stream>>>(
        node, euclid, W3, b3, b2, PA, w1c_p, w1b_p, w2_p, w1d_f, out);
    symmetrize<<<dim3(BN / 32, BN / 32, 2), dim3(32, 32), 0, stream>>>(out);
}